// Round 1
// baseline (432.390 us; speedup 1.0000x reference)
//
#include <hip/hip_runtime.h>
#include <math.h>

#define BB 2
#define NN 384
#define ND 8
#define CD 16
#define HH 128
#define LL 4
#define TT 100

__device__ __forceinline__ float silu_f(float x) {
    float s = 1.0f / (1.0f + __expf(-x));
    return x * s;
}

// ---------------- zero accumulators ----------------
__global__ void k_zero(float* accums) {
    if (threadIdx.x < 2) accums[threadIdx.x] = 0.0f;
}

// ---------------- per-batch prep: alpha_bar, mask sum, time+cond MLPs ----------------
__global__ void k_prep(const float* __restrict__ mask, const float* __restrict__ condition,
                       const int* __restrict__ timesteps,
                       const float* __restrict__ time_w1, const float* __restrict__ time_b1,
                       const float* __restrict__ time_w2, const float* __restrict__ time_b2,
                       const float* __restrict__ cond_w1, const float* __restrict__ cond_b1,
                       const float* __restrict__ cond_w2, const float* __restrict__ cond_b2,
                       float* __restrict__ tc, float* __restrict__ scal) {
    int b = blockIdx.x;
    int t = threadIdx.x; // 0..127
    __shared__ float sh[HH];
    __shared__ float sh2[HH];
    __shared__ float shc[CD];
    __shared__ float red[HH];

    int ts = timesteps[b];
    // alpha_bar cumprod (all threads redundantly, <=100 iters)
    float ab = 1.0f;
    for (int k = 0; k <= ts; ++k) {
        float beta = 1e-4f + (0.02f - 1e-4f) * ((float)k / (float)(TT - 1));
        ab *= (1.0f - beta);
    }
    if (t == 0) {
        scal[b * 4 + 0] = sqrtf(ab);
        scal[b * 4 + 1] = sqrtf(1.0f - ab);
    }
    // mask row sum
    float m = 0.0f;
    for (int j = t; j < NN; j += HH) m += mask[b * NN + j];
    red[t] = m;
    __syncthreads();
    for (int s = 64; s > 0; s >>= 1) {
        if (t < s) red[t] += red[t + s];
        __syncthreads();
    }
    if (t == 0) scal[b * 4 + 2] = red[0];

    // sinusoidal time embedding
    const int half = HH / 2;
    float factor = logf(10000.0f) / (float)(half - 1);
    float tf = (float)ts;
    float temb;
    if (t < half) temb = sinf(tf * __expf(-factor * (float)t));
    else          temb = cosf(tf * __expf(-factor * (float)(t - half)));
    sh[t] = temb;
    if (t < CD) shc[t] = condition[b * CD + t];
    __syncthreads();

    // time mlp
    float acc = time_b1[t];
    for (int k = 0; k < HH; ++k) acc += sh[k] * time_w1[k * HH + t];
    sh2[t] = silu_f(acc);
    __syncthreads();
    float acc2 = time_b2[t];
    for (int k = 0; k < HH; ++k) acc2 += sh2[k] * time_w2[k * HH + t];
    // cond mlp (shc already staged)
    float acc3 = cond_b1[t];
    for (int k = 0; k < CD; ++k) acc3 += shc[k] * cond_w1[k * HH + t];
    __syncthreads();          // everyone done reading sh/sh2
    sh[t] = silu_f(acc3);
    __syncthreads();
    float acc4 = cond_b2[t];
    for (int k = 0; k < HH; ++k) acc4 += sh[k] * cond_w2[k * HH + t];

    tc[b * HH + t] = acc2 + acc4;
}

// ---------------- per-node: noising + nodep MLP + add time/cond ----------------
__global__ void k_node_init(const float* __restrict__ node_features, const float* __restrict__ positions,
                            const float* __restrict__ feature_noise, const float* __restrict__ position_noise,
                            const float* __restrict__ nodep_w1, const float* __restrict__ nodep_b1,
                            const float* __restrict__ nodep_w2, const float* __restrict__ nodep_b2,
                            const float* __restrict__ tc, const float* __restrict__ scal,
                            float* __restrict__ state, float* __restrict__ npos) {
    int idx = blockIdx.x;
    int b = idx / NN;
    int t = threadIdx.x;
    float sab = scal[b * 4 + 0], s1ab = scal[b * 4 + 1];
    __shared__ float x[ND + 2];
    __shared__ float h1[HH];
    if (t < ND) {
        x[t] = sab * node_features[idx * ND + t] + s1ab * feature_noise[idx * ND + t];
    } else if (t < ND + 2) {
        int d = t - ND;
        float p = sab * positions[idx * 2 + d] + s1ab * position_noise[idx * 2 + d];
        x[t] = p;
        npos[idx * 2 + d] = p;
    }
    __syncthreads();
    float acc = nodep_b1[t];
    for (int k = 0; k < ND + 2; ++k) acc += x[k] * nodep_w1[k * HH + t];
    h1[t] = silu_f(acc);
    __syncthreads();
    float acc2 = nodep_b2[t];
    for (int k = 0; k < HH; ++k) acc2 += h1[k] * nodep_w2[k * HH + t];
    state[idx * HH + t] = acc2 + tc[b * HH + t];
}

// ---------------- pairwise distances ----------------
__global__ void k_dist(const float* __restrict__ npos, float* __restrict__ dist) {
    int idx = blockIdx.x * blockDim.x + threadIdx.x;
    if (idx >= BB * NN * NN) return;
    int b = idx / (NN * NN);
    int r = idx % (NN * NN);
    int i = r / NN, j = r % NN;
    float dx = npos[(b * NN + i) * 2 + 0] - npos[(b * NN + j) * 2 + 0];
    float dy = npos[(b * NN + i) * 2 + 1] - npos[(b * NN + j) * 2 + 1];
    dist[idx] = sqrtf(dx * dx + dy * dy + 1e-12f);
}

// ---------------- per-layer: ai (with eb1 folded) and aj projections ----------------
__global__ void k_aiaj(const float* __restrict__ state,
                       const float* __restrict__ ew1, const float* __restrict__ eb1,
                       float* __restrict__ ai, float* __restrict__ aj) {
    int idx = blockIdx.x;
    int t = threadIdx.x;
    __shared__ float s[HH];
    s[t] = state[idx * HH + t];
    __syncthreads();
    float a1 = eb1[t];
    float a2 = 0.0f;
    for (int k = 0; k < HH; ++k) {
        float sk = s[k];
        a1 += sk * ew1[k * HH + t];
        a2 += sk * ew1[(HH + k) * HH + t];
    }
    ai[idx * HH + t] = a1;
    aj[idx * HH + t] = a2;
}

// ---------------- per-layer hot loop: S[b,i,h] = sum_j m_j * silu(ai+aj+d*wd) ----------------
__global__ __launch_bounds__(512) void k_edge(const float* __restrict__ ai, const float* __restrict__ aj,
                                              const float* __restrict__ dist, const float* __restrict__ mask,
                                              const float* __restrict__ wd, float* __restrict__ S) {
    int idx = blockIdx.x;         // b*N + i
    int b = idx / NN;
    int t = threadIdx.x & 127;    // h
    int g = threadIdx.x >> 7;     // 0..3 j-group
    float av = ai[idx * HH + t];
    float wdt = wd[t];
    const float* ajb = aj + b * NN * HH;
    const float* db = dist + idx * NN;
    const float* mb = mask + b * NN;
    float acc = 0.0f;
    for (int j = g; j < NN; j += 4) {
        float d = db[j];
        float mj = mb[j];
        float v = av + ajb[j * HH + t] + d * wdt;
        acc += mj * silu_f(v);
    }
    __shared__ float red[4][HH];
    red[g][t] = acc;
    __syncthreads();
    if (g == 0) {
        S[idx * HH + t] = red[0][t] + red[1][t] + red[2][t] + red[3][t];
    }
}

// ---------------- per-layer: agg = mi*(S@ew2 + msum*eb2)/denom ; node MLP ; state += upd*mi ----------------
__global__ void k_update(const float* __restrict__ S, const float* __restrict__ mask,
                         const float* __restrict__ scal,
                         const float* __restrict__ ew2, const float* __restrict__ eb2,
                         const float* __restrict__ nw1, const float* __restrict__ nb1,
                         const float* __restrict__ nw2, const float* __restrict__ nb2,
                         float* __restrict__ state) {
    int idx = blockIdx.x;
    int b = idx / NN, i = idx % NN;
    int t = threadIdx.x;
    __shared__ float sS[HH], ss[HH], sagg[HH], su[HH];
    sS[t] = S[idx * HH + t];
    ss[t] = state[idx * HH + t];
    __syncthreads();
    float mi = mask[b * NN + i];
    float msum = scal[b * 4 + 2];
    float denom = fmaxf(mi * msum, 1.0f);
    float a = 0.0f;
    for (int k = 0; k < HH; ++k) a += sS[k] * ew2[k * HH + t];
    a = mi * (a + msum * eb2[t]) / denom;
    sagg[t] = a;
    __syncthreads();
    float u = nb1[t];
    for (int k = 0; k < HH; ++k) {
        u += ss[k] * nw1[k * HH + t];
        u += sagg[k] * nw1[(HH + k) * HH + t];
    }
    su[t] = silu_f(u);
    __syncthreads();
    float upd = nb2[t];
    for (int k = 0; k < HH; ++k) upd += su[k] * nw2[k * HH + t];
    state[idx * HH + t] = ss[t] + upd * mi;
}

// ---------------- heads: pred_fn / pred_pn losses ----------------
__global__ void k_heads(const float* __restrict__ state, const float* __restrict__ mask,
                        const float* __restrict__ feature_noise, const float* __restrict__ position_noise,
                        const float* __restrict__ fw1, const float* __restrict__ fb1,
                        const float* __restrict__ fw2, const float* __restrict__ fb2,
                        const float* __restrict__ pw1, const float* __restrict__ pb1,
                        const float* __restrict__ pw2, const float* __restrict__ pb2,
                        float* __restrict__ accums) {
    int idx = blockIdx.x;
    int b = idx / NN, i = idx % NN;
    int t = threadIdx.x;
    __shared__ float ss[HH], h1[HH], h2[HH];
    __shared__ float lred[2];
    ss[t] = state[idx * HH + t];
    __syncthreads();
    float a = fb1[t];
    for (int k = 0; k < HH; ++k) a += ss[k] * fw1[k * HH + t];
    h1[t] = silu_f(a);
    float a2 = pb1[t];
    for (int k = 0; k < HH; ++k) a2 += ss[k] * pw1[k * HH + t];
    h2[t] = silu_f(a2);
    if (t == 0) { lred[0] = 0.0f; lred[1] = 0.0f; }
    __syncthreads();
    float mi = mask[b * NN + i];
    if (t < ND) {
        float o = fb2[t];
        for (int k = 0; k < HH; ++k) o += h1[k] * fw2[k * ND + t];
        float d = o - feature_noise[idx * ND + t];
        atomicAdd(&lred[0], mi * d * d);
    } else if (t < ND + 2) {
        int d2 = t - ND;
        float o = pb2[d2];
        for (int k = 0; k < HH; ++k) o += h2[k] * pw2[k * 2 + d2];
        float d = o - position_noise[idx * 2 + d2];
        atomicAdd(&lred[1], mi * d * d);
    }
    __syncthreads();
    if (t == 0) {
        atomicAdd(&accums[0], lred[0]);
        atomicAdd(&accums[1], lred[1]);
    }
}

// ---------------- masked mean pooling ----------------
__global__ void k_gemb(const float* __restrict__ state, const float* __restrict__ mask,
                       const float* __restrict__ scal, float* __restrict__ gemb) {
    int b = blockIdx.x;
    int t = threadIdx.x;
    float acc = 0.0f;
    for (int i = 0; i < NN; ++i) acc += state[(b * NN + i) * HH + t] * mask[b * NN + i];
    gemb[b * HH + t] = acc / fmaxf(scal[b * 4 + 2], 1.0f);
}

// ---------------- property MLP + final losses ----------------
__global__ void k_final(const float* __restrict__ gemb, const float* __restrict__ targets,
                        const float* __restrict__ pweights,
                        const float* __restrict__ w1, const float* __restrict__ b1,
                        const float* __restrict__ w2, const float* __restrict__ b2,
                        const float* __restrict__ w3, const float* __restrict__ b3,
                        const float* __restrict__ accums, const float* __restrict__ scal,
                        float* __restrict__ out) {
    int t = threadIdx.x;
    __shared__ float g[HH], h1[HH], h2[64];
    __shared__ float ploss_acc;
    if (t == 0) ploss_acc = 0.0f;
    for (int b = 0; b < BB; ++b) {
        __syncthreads();
        g[t] = gemb[b * HH + t];
        __syncthreads();
        float a = b1[t];
        for (int k = 0; k < HH; ++k) a += g[k] * w1[k * HH + t];
        h1[t] = silu_f(a);
        __syncthreads();
        if (t < 64) {
            float a2 = b2[t];
            for (int k = 0; k < HH; ++k) a2 += h1[k] * w2[k * 64 + t];
            h2[t] = silu_f(a2);
        }
        __syncthreads();
        if (t < 4) {
            float o = b3[t];
            for (int k = 0; k < 64; ++k) o += h2[k] * w3[k * 4 + t];
            float d = o - targets[b * 4 + t];
            atomicAdd(&ploss_acc, d * d * pweights[t]);
        }
    }
    __syncthreads();
    if (t == 0) {
        float msumt = fmaxf(scal[0 * 4 + 2] + scal[1 * 4 + 2], 1.0f);
        float noise = (accums[0] + accums[1]) / msumt;
        float prop = ploss_acc / (float)(BB * 4);
        out[0] = noise;
        out[1] = prop;
        out[2] = noise + prop;
    }
}

extern "C" void kernel_launch(void* const* d_in, const int* in_sizes, int n_in,
                              void* d_out, int out_size, void* d_ws, size_t ws_size,
                              hipStream_t stream) {
    const float* node_features  = (const float*)d_in[0];
    const float* positions      = (const float*)d_in[1];
    const float* mask           = (const float*)d_in[2];
    const float* condition      = (const float*)d_in[3];
    const float* targets        = (const float*)d_in[4];
    const float* pweights       = (const float*)d_in[5];
    const float* feature_noise  = (const float*)d_in[6];
    const float* position_noise = (const float*)d_in[7];
    const int*   timesteps      = (const int*)d_in[8];
    const float* time_w1 = (const float*)d_in[9];
    const float* time_b1 = (const float*)d_in[10];
    const float* time_w2 = (const float*)d_in[11];
    const float* time_b2 = (const float*)d_in[12];
    const float* cond_w1 = (const float*)d_in[13];
    const float* cond_b1 = (const float*)d_in[14];
    const float* cond_w2 = (const float*)d_in[15];
    const float* cond_b2 = (const float*)d_in[16];
    const float* nodep_w1 = (const float*)d_in[17];
    const float* nodep_b1 = (const float*)d_in[18];
    const float* nodep_w2 = (const float*)d_in[19];
    const float* nodep_b2 = (const float*)d_in[20];
    const float* edge_w1 = (const float*)d_in[21];
    const float* edge_b1 = (const float*)d_in[22];
    const float* edge_w2 = (const float*)d_in[23];
    const float* edge_b2 = (const float*)d_in[24];
    const float* nodem_w1 = (const float*)d_in[25];
    const float* nodem_b1 = (const float*)d_in[26];
    const float* nodem_w2 = (const float*)d_in[27];
    const float* nodem_b2 = (const float*)d_in[28];
    const float* feat_w1 = (const float*)d_in[29];
    const float* feat_b1 = (const float*)d_in[30];
    const float* feat_w2 = (const float*)d_in[31];
    const float* feat_b2 = (const float*)d_in[32];
    const float* pos_w1 = (const float*)d_in[33];
    const float* pos_b1 = (const float*)d_in[34];
    const float* pos_w2 = (const float*)d_in[35];
    const float* pos_b2 = (const float*)d_in[36];
    const float* prop_w1 = (const float*)d_in[37];
    const float* prop_b1 = (const float*)d_in[38];
    const float* prop_w2 = (const float*)d_in[39];
    const float* prop_b2 = (const float*)d_in[40];
    const float* prop_w3 = (const float*)d_in[41];
    const float* prop_b3 = (const float*)d_in[42];

    float* ws = (float*)d_ws;
    float* npos   = ws;                         // B*N*2        = 1536
    float* state  = npos + BB * NN * 2;         // B*N*H        = 98304
    float* dist   = state + BB * NN * HH;       // B*N*N        = 294912
    float* ai     = dist + BB * NN * NN;        // B*N*H
    float* aj     = ai + BB * NN * HH;          // B*N*H
    float* Ssum   = aj + BB * NN * HH;          // B*N*H
    float* tc     = Ssum + BB * NN * HH;        // B*H
    float* scal   = tc + BB * HH;               // B*4
    float* accums = scal + BB * 4;              // 2
    float* gemb   = accums + 2;                 // B*H

    float* outp = (float*)d_out;

    k_zero<<<1, 64, 0, stream>>>(accums);
    k_prep<<<BB, HH, 0, stream>>>(mask, condition, timesteps,
                                  time_w1, time_b1, time_w2, time_b2,
                                  cond_w1, cond_b1, cond_w2, cond_b2,
                                  tc, scal);
    k_node_init<<<BB * NN, HH, 0, stream>>>(node_features, positions, feature_noise, position_noise,
                                            nodep_w1, nodep_b1, nodep_w2, nodep_b2,
                                            tc, scal, state, npos);
    k_dist<<<(BB * NN * NN + 255) / 256, 256, 0, stream>>>(npos, dist);

    for (int l = 0; l < LL; ++l) {
        const float* ew1 = edge_w1 + (size_t)l * (2 * HH + 1) * HH;
        const float* eb1 = edge_b1 + (size_t)l * HH;
        const float* ew2 = edge_w2 + (size_t)l * HH * HH;
        const float* eb2 = edge_b2 + (size_t)l * HH;
        const float* nw1 = nodem_w1 + (size_t)l * 2 * HH * HH;
        const float* nb1 = nodem_b1 + (size_t)l * HH;
        const float* nw2 = nodem_w2 + (size_t)l * HH * HH;
        const float* nb2 = nodem_b2 + (size_t)l * HH;
        const float* wd  = ew1 + (size_t)(2 * HH) * HH; // row 256 of ew1

        k_aiaj<<<BB * NN, HH, 0, stream>>>(state, ew1, eb1, ai, aj);
        k_edge<<<BB * NN, 512, 0, stream>>>(ai, aj, dist, mask, wd, Ssum);
        k_update<<<BB * NN, HH, 0, stream>>>(Ssum, mask, scal, ew2, eb2,
                                             nw1, nb1, nw2, nb2, state);
    }

    k_heads<<<BB * NN, HH, 0, stream>>>(state, mask, feature_noise, position_noise,
                                        feat_w1, feat_b1, feat_w2, feat_b2,
                                        pos_w1, pos_b1, pos_w2, pos_b2, accums);
    k_gemb<<<BB, HH, 0, stream>>>(state, mask, scal, gemb);
    k_final<<<1, HH, 0, stream>>>(gemb, targets, pweights,
                                  prop_w1, prop_b1, prop_w2, prop_b2, prop_w3, prop_b3,
                                  accums, scal, outp);
}